// Round 9
// baseline (403.198 us; speedup 1.0000x reference)
//
#include <hip/hip_runtime.h>
#include <hip/hip_bf16.h>
#include <math.h>

#define DIM 1024
#define NTOK 2048   // B*L = 4*512
#define LSEQ 512
#define NB 4
#define DTR 64
#define DST 16
#define NCH 8
#define TCH 64      // LSEQ / NCH

typedef unsigned short ushort_t;
typedef __attribute__((ext_vector_type(8))) short bf16x8;
typedef __attribute__((ext_vector_type(4))) float f32x4;

__device__ __forceinline__ float softplus_f(float x) {
    return (x > 20.f) ? x : log1pf(__expf(x));
}
__device__ __forceinline__ ushort_t to_bf16_bits(float f) {
    __hip_bfloat16 h = __float2bfloat16(f);
    return *(ushort_t*)&h;
}
__device__ __forceinline__ float bf16_bits_to_f(ushort_t b) {
    return __uint_as_float(((unsigned int)b) << 16);
}
// x + dpp_perm(x); ctrl: 0xB1=quad xor1, 0x4E=quad xor2, 0x124=row_ror:4, 0x128=row_ror:8
template<int CTRL>
__device__ __forceinline__ float dpp_add(float x) {
    int xi = __float_as_int(x);
    int yi = __builtin_amdgcn_update_dpp(xi, xi, CTRL, 0xF, 0xF, false);
    return x + __int_as_float(yi);
}

// ---------------- weight transpose + bf16 convert: Wt[n][k] = bf16(W[k][n]) ----------------
__global__ __launch_bounds__(256) void wconv_kernel(
    const float* __restrict__ W0, const float* __restrict__ W1, const float* __restrict__ W2,
    ushort_t* __restrict__ T0, ushort_t* __restrict__ T1, ushort_t* __restrict__ T2) {
    const float* W = blockIdx.z == 0 ? W0 : blockIdx.z == 1 ? W1 : W2;
    ushort_t* T    = blockIdx.z == 0 ? T0 : blockIdx.z == 1 ? T1 : T2;
    __shared__ float tile[64][65];
    const int k0 = blockIdx.x * 64, n0 = blockIdx.y * 64;
    const int tid = threadIdx.x;
    #pragma unroll
    for (int p = 0; p < 16; ++p) {
        int idx = p * 256 + tid;
        int i = idx >> 6, j = idx & 63;
        tile[i][j] = W[(size_t)(k0 + i) * DIM + n0 + j];
    }
    __syncthreads();
    #pragma unroll
    for (int p = 0; p < 16; ++p) {
        int idx = p * 256 + tid;
        int j = idx >> 6, i = idx & 63;
        T[(size_t)(n0 + j) * DIM + k0 + i] = to_bf16_bits(tile[i][j]);
    }
}

// ---------------- LayerNorm -> bf16 ----------------
__global__ __launch_bounds__(256) void ln_kernel(
    const float* __restrict__ x, const float* __restrict__ gamma,
    const float* __restrict__ beta, ushort_t* __restrict__ out) {
    const int row = blockIdx.x;
    const int tid = threadIdx.x;
    const float4* xr = (const float4*)(x + (size_t)row * DIM);
    float4 v = xr[tid];
    float s  = v.x + v.y + v.z + v.w;
    float sq = v.x*v.x + v.y*v.y + v.z*v.z + v.w*v.w;
    for (int o = 32; o > 0; o >>= 1) {
        s  += __shfl_down(s, o);
        sq += __shfl_down(sq, o);
    }
    __shared__ float red[8];
    if ((tid & 63) == 0) { red[tid >> 6] = s; red[4 + (tid >> 6)] = sq; }
    __syncthreads();
    float st  = red[0] + red[1] + red[2] + red[3];
    float sqt = red[4] + red[5] + red[6] + red[7];
    float mu = st * (1.f / DIM);
    float var = sqt * (1.f / DIM) - mu * mu;
    float rstd = rsqrtf(var + 1e-6f);
    float4 g = ((const float4*)gamma)[tid];
    float4 bt = ((const float4*)beta)[tid];
    ushort4 ob;
    ob.x = to_bf16_bits((v.x - mu) * rstd * g.x + bt.x);
    ob.y = to_bf16_bits((v.y - mu) * rstd * g.y + bt.y);
    ob.z = to_bf16_bits((v.z - mu) * rstd * g.z + bt.z);
    ob.w = to_bf16_bits((v.w - mu) * rstd * g.w + bt.w);
    ((ushort4*)(out + (size_t)row * DIM))[tid] = ob;
}

// ---------------- bf16 MFMA GEMM, 64x64 tile, BK=64, double-buffered LDS ----------------
// 4 waves in 2x2; wave tile 32x32 = 2x2 frags of 16x16.
// LDS [row][k8slot*8], k8slot = k8 ^ (row&7); pre-swizzled global source (rule #21).
// ACT 0: outb = bf16(v) [tok][DIM], outf = silu(v) [tok][DIM].
// ACT 1: outb = bf16(softplus) [tok][DIM], outbT = bf16(softplus) transposed [DIM][NTOK].
// ACT 2: outbT = bf16(softplus) transposed [DIM][NTOK] only.
template<int ACT>
__global__ __launch_bounds__(256) void mfma_gemm(
    const ushort_t* __restrict__ A, const ushort_t* __restrict__ Bt,
    const float* __restrict__ bias, ushort_t* __restrict__ outb,
    ushort_t* __restrict__ outbT, float* __restrict__ outf) {
    __shared__ __align__(16) ushort_t Asl[2][64 * 64];
    __shared__ __align__(16) ushort_t Bsl[2][64 * 64];
    const int tid = threadIdx.x;
    const int bm = blockIdx.y * 64;
    const int bn = blockIdx.x * 64;
    const int lane = tid & 63;
    const int wid = tid >> 6;
    const int r  = lane & 15;
    const int kg = lane >> 4;            // 0..3
    const int wm = wid >> 1, wn = wid & 1;

    f32x4 acc[2][2] = {};

    auto STAGE = [&](int buf, int k0) {
        #pragma unroll
        for (int q = 0; q < 2; ++q) {
            int c = q * 256 + tid;
            int row = c >> 3;
            int ksl = ((c & 7) ^ (row & 7)) << 3;
            __builtin_amdgcn_global_load_lds(
                (const __attribute__((address_space(1))) void*)(A + (size_t)(bm + row) * DIM + k0 + ksl),
                (__attribute__((address_space(3))) void*)(&Asl[buf][c * 8]), 16, 0, 0);
        }
        #pragma unroll
        for (int q = 0; q < 2; ++q) {
            int c = q * 256 + tid;
            int row = c >> 3;
            int ksl = ((c & 7) ^ (row & 7)) << 3;
            __builtin_amdgcn_global_load_lds(
                (const __attribute__((address_space(1))) void*)(Bt + (size_t)(bn + row) * DIM + k0 + ksl),
                (__attribute__((address_space(3))) void*)(&Bsl[buf][c * 8]), 16, 0, 0);
        }
    };

    STAGE(0, 0);
    __syncthreads();                 // buf0 staged (syncthreads drains vmcnt)
    int cur = 0;
    for (int t = 0; t < DIM / 64; ++t) {
        if (t + 1 < DIM / 64) STAGE(cur ^ 1, (t + 1) * 64);   // issue next-tile loads
        #pragma unroll
        for (int kk = 0; kk < 2; ++kk) {
            const int sw = ((kk * 4 + kg) ^ (r & 7)) << 3;
            bf16x8 af[2], bfr[2];
            #pragma unroll
            for (int mi = 0; mi < 2; ++mi)
                af[mi] = *(const bf16x8*)&Asl[cur][(wm * 32 + mi * 16 + r) * 64 + sw];
            #pragma unroll
            for (int nj = 0; nj < 2; ++nj)
                bfr[nj] = *(const bf16x8*)&Bsl[cur][(wn * 32 + nj * 16 + r) * 64 + sw];
            #pragma unroll
            for (int mi = 0; mi < 2; ++mi)
                #pragma unroll
                for (int nj = 0; nj < 2; ++nj)
                    acc[mi][nj] = __builtin_amdgcn_mfma_f32_16x16x32_bf16(af[mi], bfr[nj], acc[mi][nj], 0, 0, 0);
        }
        __syncthreads();             // drains next-tile loads + everyone done reading cur
        cur ^= 1;
    }

    // epilogue: row = bm + wm*32 + mi*16 + kg*4 + j, col = bn + wn*32 + nj*16 + r
    #pragma unroll
    for (int nj = 0; nj < 2; ++nj) {
        const int col = bn + wn * 32 + nj * 16 + r;
        const float bv = bias[col];
        #pragma unroll
        for (int mi = 0; mi < 2; ++mi) {
            const int rowb = bm + wm * 32 + mi * 16 + kg * 4;
            if (ACT == 0) {
                #pragma unroll
                for (int j = 0; j < 4; ++j) {
                    float v = acc[mi][nj][j] + bv;
                    size_t idx = (size_t)(rowb + j) * DIM + col;
                    outb[idx] = to_bf16_bits(v);
                    outf[idx] = v / (1.f + __expf(-v));   // silu
                }
            } else {
                float sp[4];
                #pragma unroll
                for (int j = 0; j < 4; ++j)
                    sp[j] = softplus_f(acc[mi][nj][j] + bv);
                if (ACT == 1) {
                    #pragma unroll
                    for (int j = 0; j < 4; ++j)
                        outb[(size_t)(rowb + j) * DIM + col] = to_bf16_bits(sp[j]);
                }
                ushort4 tp;
                tp.x = to_bf16_bits(sp[0]); tp.y = to_bf16_bits(sp[1]);
                tp.z = to_bf16_bits(sp[2]); tp.w = to_bf16_bits(sp[3]);
                *(ushort4*)&outbT[(size_t)col * NTOK + rowb] = tp;
            }
        }
    }
}

// ---------------- Wcomb precompute ----------------
// WcombT[s][j][i] = bf16( sum_r W_x[i][r] * W_dt[r][j] ),  r < 64
// aux blocks (blockIdx.y==16): WxBCt[s][c][i] = bf16(W_x[i][64+c]) (c<32);
//                              bcomb[s][j] = b_dt[j] + sum_r b_x[r]*W_dt[r][j]
__global__ __launch_bounds__(256) void wcomb_kernel(
    const float* __restrict__ Wx1, const float* __restrict__ Wdt1,
    const float* __restrict__ bx1, const float* __restrict__ bdt1,
    const float* __restrict__ Wx2, const float* __restrict__ Wdt2,
    const float* __restrict__ bx2, const float* __restrict__ bdt2,
    ushort_t* __restrict__ WcombT, ushort_t* __restrict__ WxBCt,
    float* __restrict__ bcomb) {
    const int s = blockIdx.z;
    const float* __restrict__ Wx  = s ? Wx2  : Wx1;   // [1024][96]
    const float* __restrict__ Wdt = s ? Wdt2 : Wdt1;  // [64][1024]
    const float* __restrict__ bx  = s ? bx2  : bx1;
    const float* __restrict__ bdt = s ? bdt2 : bdt1;
    const int tid = threadIdx.x;
    __shared__ float Xs[64][65];   // [i][r]
    __shared__ float Ds[64][65];   // [r][j]
    if (blockIdx.y == 16) {
        const int i0 = blockIdx.x * 64;
        #pragma unroll
        for (int p = 0; p < 8; ++p) {
            int idx = p * 256 + tid;
            int c = idx >> 6, i = i0 + (idx & 63);
            WxBCt[((size_t)s * 32 + c) * DIM + i] = to_bf16_bits(Wx[(size_t)i * 96 + 64 + c]);
        }
        if (tid < 64) {
            int j = i0 + tid;
            float acc = bdt[j];
            for (int r = 0; r < 64; ++r) acc = fmaf(bx[r], Wdt[(size_t)r * DIM + j], acc);
            bcomb[(size_t)s * DIM + j] = acc;
        }
        return;
    }
    const int i0 = blockIdx.x * 64, j0 = blockIdx.y * 64;
    #pragma unroll
    for (int p = 0; p < 16; ++p) {
        int idx = p * 256 + tid;
        int i = idx >> 6, r = idx & 63;
        Xs[i][r] = Wx[(size_t)(i0 + i) * 96 + r];
    }
    #pragma unroll
    for (int p = 0; p < 16; ++p) {
        int idx = p * 256 + tid;
        int r = idx >> 6, j = idx & 63;
        Ds[r][j] = Wdt[(size_t)r * DIM + j0 + j];
    }
    __syncthreads();
    const int tj = (tid >> 4) * 4, ti = (tid & 15) * 4;
    float acc[4][4] = {};
    for (int r = 0; r < 64; ++r) {
        float a[4], b[4];
        #pragma unroll
        for (int q = 0; q < 4; ++q) a[q] = Ds[r][tj + q];
        #pragma unroll
        for (int q = 0; q < 4; ++q) b[q] = Xs[ti + q][r];
        #pragma unroll
        for (int ji = 0; ji < 4; ++ji)
            #pragma unroll
            for (int ii = 0; ii < 4; ++ii)
                acc[ji][ii] = fmaf(a[ji], b[ii], acc[ji][ii]);
    }
    #pragma unroll
    for (int ji = 0; ji < 4; ++ji)
        #pragma unroll
        for (int ii = 0; ii < 4; ++ii)
            WcombT[((size_t)s * DIM + j0 + tj + ji) * DIM + i0 + ti + ii] = to_bf16_bits(acc[ji][ii]);
}

// ---------------- BC^T = (u @ W_x[:,64:96] + b_x[64:96])^T, split-K MFMA + atomics ----------------
// grid (NTOK/64, 4 k-chunks, 2 s); BCT [2][32][NTOK] fp32, pre-zeroed.
__global__ __launch_bounds__(256) void bc_kernel(
    const ushort_t* __restrict__ u1b, const ushort_t* __restrict__ u2b,
    const ushort_t* __restrict__ WxBCt,
    const float* __restrict__ bx1, const float* __restrict__ bx2,
    float* __restrict__ BCT) {
    const int s = blockIdx.z;
    const ushort_t* __restrict__ u  = s ? u2b : u1b;
    const ushort_t* __restrict__ Bt = WxBCt + (size_t)s * 32 * DIM;
    const float* __restrict__ bx    = s ? bx2 : bx1;
    const int bm = blockIdx.x * 64;
    const int kbase = blockIdx.y * 256;
    __shared__ __align__(16) ushort_t Asl[2][64 * 64];
    __shared__ __align__(16) ushort_t Bsl[2][32 * 64];
    const int tid = threadIdx.x;
    const int lane = tid & 63, wid = tid >> 6;
    const int r = lane & 15, kg = lane >> 4;
    f32x4 acc[2] = {};
    auto STAGE = [&](int buf, int k0) {
        #pragma unroll
        for (int q = 0; q < 2; ++q) {
            int c = q * 256 + tid;
            int row = c >> 3;
            int ksl = ((c & 7) ^ (row & 7)) << 3;
            __builtin_amdgcn_global_load_lds(
                (const __attribute__((address_space(1))) void*)(u + (size_t)(bm + row) * DIM + k0 + ksl),
                (__attribute__((address_space(3))) void*)(&Asl[buf][c * 8]), 16, 0, 0);
        }
        {
            int c = tid;
            int row = c >> 3;
            int ksl = ((c & 7) ^ (row & 7)) << 3;
            __builtin_amdgcn_global_load_lds(
                (const __attribute__((address_space(1))) void*)(Bt + (size_t)row * DIM + k0 + ksl),
                (__attribute__((address_space(3))) void*)(&Bsl[buf][c * 8]), 16, 0, 0);
        }
    };
    STAGE(0, kbase);
    __syncthreads();
    int cur = 0;
    for (int t = 0; t < 4; ++t) {
        if (t + 1 < 4) STAGE(cur ^ 1, kbase + (t + 1) * 64);
        #pragma unroll
        for (int kk = 0; kk < 2; ++kk) {
            const int sw = ((kk * 4 + kg) ^ (r & 7)) << 3;
            bf16x8 af = *(const bf16x8*)&Asl[cur][(wid * 16 + r) * 64 + sw];
            #pragma unroll
            for (int nj = 0; nj < 2; ++nj) {
                bf16x8 bfr = *(const bf16x8*)&Bsl[cur][(nj * 16 + r) * 64 + sw];
                acc[nj] = __builtin_amdgcn_mfma_f32_16x16x32_bf16(af, bfr, acc[nj], 0, 0, 0);
            }
        }
        __syncthreads();
        cur ^= 1;
    }
    const bool kc0 = (blockIdx.y == 0);
    #pragma unroll
    for (int nj = 0; nj < 2; ++nj) {
        const int col = nj * 16 + r;
        #pragma unroll
        for (int j = 0; j < 4; ++j) {
            const int row = bm + wid * 16 + kg * 4 + j;
            float v = acc[nj][j];
            if (kc0) v += bx[64 + col];
            atomicAdd(&BCT[((size_t)s * 32 + col) * NTOK + row], v);
        }
    }
}

// ---------------- fused chunked selective scan (pass1 + combine + pass2 in-block) ----------------
// block = 2 d-values x 16 n x 8 chunks = 256 threads; grid (DIM/2, NB, 2).
// All step-direction data transposed: deltaT/uT bf16 [DIM][NTOK], BCT fp32 [2][32][NTOK].
__global__ __launch_bounds__(256) void scan_fused(
    const ushort_t* __restrict__ dT1, const ushort_t* __restrict__ uT1,
    const float* __restrict__ Alog1, const float* __restrict__ D1p, float* __restrict__ y1,
    const ushort_t* __restrict__ dT2, const ushort_t* __restrict__ uT2,
    const float* __restrict__ Alog2, const float* __restrict__ D2p, float* __restrict__ y2,
    const float* __restrict__ BCT) {
    const int s = blockIdx.z;
    const ushort_t* __restrict__ dT = s ? dT2 : dT1;
    const ushort_t* __restrict__ uT = s ? uT2 : uT1;
    const float* __restrict__ Alog  = s ? Alog2 : Alog1;
    const float* __restrict__ Dp    = s ? D2p : D1p;
    float* __restrict__ y           = s ? y2 : y1;
    const int tid = threadIdx.x;
    const int n  = tid & 15;
    const int c  = (tid >> 4) & 7;
    const int dd = tid >> 7;
    const int d  = blockIdx.x * 2 + dd;
    const int b  = blockIdx.y;
    const int tok0 = b * LSEQ + c * TCH;
    const float a = -__expf(Alog[d * DST + n]);

    const ushort_t* __restrict__ dlp = dT + d * NTOK + tok0;
    const ushort_t* __restrict__ uup = uT + d * NTOK + tok0;
    const float* __restrict__ Bp = BCT + (s * 32 + n) * NTOK + tok0;
    const float* __restrict__ Cp = Bp + 16 * NTOK;

    __shared__ float rL[2][16][8];
    __shared__ float sdL[2][8];
    __shared__ float hinL[2][16][8];

    // pass 1: chunk-local scan from h=0; collect chunk-final h and sum(delta)
    float h = 0.f, sd = 0.f;
    for (int t = 0; t < TCH; t += 8) {
        bf16x8 dl8 = *(const bf16x8*)(dlp + t);
        bf16x8 uu8 = *(const bf16x8*)(uup + t);
        f32x4 B0 = *(const f32x4*)(Bp + t);
        f32x4 B1 = *(const f32x4*)(Bp + t + 4);
        #pragma unroll
        for (int j = 0; j < 8; ++j) {
            float dl = bf16_bits_to_f((ushort_t)dl8[j]);
            float uu = bf16_bits_to_f((ushort_t)uu8[j]);
            float Bn = (j < 4) ? B0[j] : B1[j - 4];
            float e  = __expf(dl * a);
            h = fmaf(e, h, dl * Bn * uu);
            sd += dl;
        }
    }
    rL[dd][n][c] = h;
    if (n == 0) sdL[dd][c] = sd;
    __syncthreads();
    // combine: 32 threads each scan 8 chunks serially for one (dd,n)
    if (tid < 32) {
        const int dc = tid >> 4, nc = tid & 15;
        const float ac = -__expf(Alog[(blockIdx.x * 2 + dc) * DST + nc]);
        float hp = 0.f;
        #pragma unroll
        for (int cc = 0; cc < 8; ++cc) {
            float P  = __expf(ac * sdL[dc][cc]);
            float rc = rL[dc][nc][cc];
            hinL[dc][nc][cc] = hp;
            hp = fmaf(P, hp, rc);
        }
    }
    __syncthreads();
    // pass 2: rerun chunk from true h_in, emit y
    h = hinL[dd][n][c];
    const float dcf = Dp[d];
    float* __restrict__ yp = y + (size_t)tok0 * DIM + d;
    for (int t = 0; t < TCH; t += 8) {
        bf16x8 dl8 = *(const bf16x8*)(dlp + t);
        bf16x8 uu8 = *(const bf16x8*)(uup + t);
        f32x4 B0 = *(const f32x4*)(Bp + t);
        f32x4 B1 = *(const f32x4*)(Bp + t + 4);
        f32x4 C0 = *(const f32x4*)(Cp + t);
        f32x4 C1 = *(const f32x4*)(Cp + t + 4);
        #pragma unroll
        for (int j = 0; j < 8; ++j) {
            float dl = bf16_bits_to_f((ushort_t)dl8[j]);
            float uu = bf16_bits_to_f((ushort_t)uu8[j]);
            float Bn = (j < 4) ? B0[j] : B1[j - 4];
            float Cn = (j < 4) ? C0[j] : C1[j - 4];
            float e  = __expf(dl * a);
            h = fmaf(e, h, dl * Bn * uu);
            float p = h * Cn;
            p = dpp_add<0xB1>(p);
            p = dpp_add<0x4E>(p);
            p = dpp_add<0x124>(p);
            p = dpp_add<0x128>(p);
            if (n == 0) yp[(t + j) * DIM] = fmaf(uu, dcf, p);
        }
    }
}

// ---------------- out = (y1 + y2) * z + skip  (z lives in d_out) ----------------
__global__ __launch_bounds__(256) void final_kernel(
    const float* __restrict__ y1, const float* __restrict__ y2,
    const float* __restrict__ skip, float* io) {
    const int i = blockIdx.x * 256 + threadIdx.x;
    float4 a = ((const float4*)y1)[i];
    float4 b = ((const float4*)y2)[i];
    float4 sk = ((const float4*)skip)[i];
    float4 z = ((float4*)io)[i];
    float4 o;
    o.x = (a.x + b.x) * z.x + sk.x;
    o.y = (a.y + b.y) * z.y + sk.y;
    o.z = (a.z + b.z) * z.z + sk.z;
    o.w = (a.w + b.w) * z.w + sk.w;
    ((float4*)io)[i] = o;
}

extern "C" void kernel_launch(void* const* d_in, const int* in_sizes, int n_in,
                              void* d_out, int out_size, void* d_ws, size_t ws_size,
                              hipStream_t stream) {
    const float* inputs = (const float*)d_in[0];
    const float* gamma  = (const float*)d_in[1];
    const float* beta   = (const float*)d_in[2];
    const float* W_proj = (const float*)d_in[3];
    const float* b_proj = (const float*)d_in[4];
    const float* W_fc   = (const float*)d_in[5];
    const float* b_fc   = (const float*)d_in[6];
    const float* W_bc   = (const float*)d_in[7];
    const float* b_bc   = (const float*)d_in[8];
    const float* W_x1   = (const float*)d_in[9];
    const float* b_x1   = (const float*)d_in[10];
    const float* W_dt1  = (const float*)d_in[11];
    const float* b_dt1  = (const float*)d_in[12];
    const float* A_log1 = (const float*)d_in[13];
    const float* D1     = (const float*)d_in[14];
    const float* W_x2   = (const float*)d_in[15];
    const float* b_x2   = (const float*)d_in[16];
    const float* W_dt2  = (const float*)d_in[17];
    const float* b_dt2  = (const float*)d_in[18];
    const float* A_log2 = (const float*)d_in[19];
    const float* D2     = (const float*)d_in[20];
    float* out = (float*)d_out;
    char* wsb  = (char*)d_ws;

    // workspace layout (~46.5 MB peak), liveness-overlaid:
    ushort_t* xln_bf   = (ushort_t*)wsb;                         // 0-4MB (dead after proj GEMM)
    ushort_t* proj_bf  = (ushort_t*)(wsb + (4u << 20));          // 4-8MB (dead after u GEMMs)
    float*    y1       = (float*)wsb;                            // 0-8MB (scan output; overlays xln/proj)
    ushort_t* u1t      = (ushort_t*)(wsb + (8u << 20));          // 8-12MB bf16 T [DIM][NTOK]
    ushort_t* u2t      = (ushort_t*)(wsb + (12u << 20));         // 12-16MB
    float*    y2       = (float*)(wsb + (16u << 20));            // 16-24MB
    ushort_t* u1b      = (ushort_t*)(wsb + (24u << 20));         // 24-28MB (dead after delta GEMMs)
    ushort_t* u2b      = (ushort_t*)(wsb + (28u << 20));         // 28-32MB
    ushort_t* delta1T  = (ushort_t*)(wsb + (32u << 20));         // 32-36MB bf16 T
    ushort_t* delta2T  = (ushort_t*)(wsb + (36u << 20));         // 36-40MB
    ushort_t* WtP      = (ushort_t*)(wsb + (40u << 20));         // 40-42MB (dead after proj GEMM)
    ushort_t* WtF      = (ushort_t*)(wsb + (42u << 20));         // 42-44MB (dead after u1 GEMM)
    ushort_t* WtB      = (ushort_t*)(wsb + (44u << 20));         // 44-46MB (dead after u2 GEMM)
    ushort_t* WxBCt    = (ushort_t*)(wsb + (40u << 20));         // 128KB (overlays WtP)
    float*    bcomb    = (float*)(wsb + (41u << 20));            // 8KB
    ushort_t* WcombT   = (ushort_t*)(wsb + (42u << 20));         // 4MB (overlays WtF/WtB)
    float*    BCT      = (float*)(wsb + (46u << 20));            // 512KB [2][32][NTOK]
    float*    zbuf     = out;                                    // z = silu(proj) staged in d_out

    wconv_kernel<<<dim3(16, 16, 3), 256, 0, stream>>>(W_proj, W_fc, W_bc, WtP, WtF, WtB);
    ln_kernel<<<NTOK, 256, 0, stream>>>(inputs, gamma, beta, xln_bf);
    mfma_gemm<0><<<dim3(DIM / 64, NTOK / 64), 256, 0, stream>>>(xln_bf, WtP, b_proj, proj_bf, nullptr, zbuf);
    mfma_gemm<1><<<dim3(DIM / 64, NTOK / 64), 256, 0, stream>>>(proj_bf, WtF, b_fc, u1b, u1t, nullptr);
    mfma_gemm<1><<<dim3(DIM / 64, NTOK / 64), 256, 0, stream>>>(proj_bf, WtB, b_bc, u2b, u2t, nullptr);
    wcomb_kernel<<<dim3(16, 17, 2), 256, 0, stream>>>(W_x1, W_dt1, b_x1, b_dt1,
                                                      W_x2, W_dt2, b_x2, b_dt2,
                                                      WcombT, WxBCt, bcomb);
    hipMemsetAsync(BCT, 0, (size_t)2 * 32 * NTOK * sizeof(float), stream);
    bc_kernel<<<dim3(NTOK / 64, 4, 2), 256, 0, stream>>>(u1b, u2b, WxBCt, b_x1, b_x2, BCT);
    mfma_gemm<2><<<dim3(DIM / 64, NTOK / 64), 256, 0, stream>>>(u1b, WcombT, bcomb, nullptr, delta1T, nullptr);
    mfma_gemm<2><<<dim3(DIM / 64, NTOK / 64), 256, 0, stream>>>(u2b, WcombT + (size_t)DIM * DIM,
                                                                bcomb + DIM, nullptr, delta2T, nullptr);
    scan_fused<<<dim3(DIM / 2, NB, 2), 256, 0, stream>>>(delta1T, u1t, A_log1, D1, y1,
                                                         delta2T, u2t, A_log2, D2, y2, BCT);
    final_kernel<<<(size_t)NTOK * DIM / 4 / 256, 256, 0, stream>>>(y1, y2, inputs, out);
}

// Round 10
// 355.576 us; speedup vs baseline: 1.1339x; 1.1339x over previous
//
#include <hip/hip_runtime.h>
#include <hip/hip_bf16.h>
#include <math.h>

#define DIM 1024
#define NTOK 2048   // B*L = 4*512
#define LSEQ 512
#define NB 4
#define DTR 64
#define DST 16
#define NCH 8
#define TCH 64      // LSEQ / NCH

typedef unsigned short ushort_t;
typedef __attribute__((ext_vector_type(8))) short bf16x8;
typedef __attribute__((ext_vector_type(4))) float f32x4;

__device__ __forceinline__ float softplus_f(float x) {
    return (x > 20.f) ? x : log1pf(__expf(x));
}
__device__ __forceinline__ ushort_t to_bf16_bits(float f) {
    __hip_bfloat16 h = __float2bfloat16(f);
    return *(ushort_t*)&h;
}
__device__ __forceinline__ float bf16_bits_to_f(ushort_t b) {
    return __uint_as_float(((unsigned int)b) << 16);
}
// x + dpp_perm(x); ctrl: 0xB1=quad xor1, 0x4E=quad xor2, 0x124=row_ror:4, 0x128=row_ror:8
template<int CTRL>
__device__ __forceinline__ float dpp_add(float x) {
    int xi = __float_as_int(x);
    int yi = __builtin_amdgcn_update_dpp(xi, xi, CTRL, 0xF, 0xF, false);
    return x + __int_as_float(yi);
}

// ---------------- weight transpose + bf16 convert: Wt[n][k] = bf16(W[k][n]) ----------------
__global__ __launch_bounds__(256) void wconv_kernel(
    const float* __restrict__ W0, const float* __restrict__ W1, const float* __restrict__ W2,
    ushort_t* __restrict__ T0, ushort_t* __restrict__ T1, ushort_t* __restrict__ T2) {
    const float* W = blockIdx.z == 0 ? W0 : blockIdx.z == 1 ? W1 : W2;
    ushort_t* T    = blockIdx.z == 0 ? T0 : blockIdx.z == 1 ? T1 : T2;
    __shared__ float tile[64][65];
    const int k0 = blockIdx.x * 64, n0 = blockIdx.y * 64;
    const int tid = threadIdx.x;
    #pragma unroll
    for (int p = 0; p < 16; ++p) {
        int idx = p * 256 + tid;
        int i = idx >> 6, j = idx & 63;
        tile[i][j] = W[(size_t)(k0 + i) * DIM + n0 + j];
    }
    __syncthreads();
    #pragma unroll
    for (int p = 0; p < 16; ++p) {
        int idx = p * 256 + tid;
        int j = idx >> 6, i = idx & 63;
        T[(size_t)(n0 + j) * DIM + k0 + i] = to_bf16_bits(tile[i][j]);
    }
}

// ---------------- LayerNorm -> bf16 ----------------
__global__ __launch_bounds__(256) void ln_kernel(
    const float* __restrict__ x, const float* __restrict__ gamma,
    const float* __restrict__ beta, ushort_t* __restrict__ out) {
    const int row = blockIdx.x;
    const int tid = threadIdx.x;
    const float4* xr = (const float4*)(x + (size_t)row * DIM);
    float4 v = xr[tid];
    float s  = v.x + v.y + v.z + v.w;
    float sq = v.x*v.x + v.y*v.y + v.z*v.z + v.w*v.w;
    for (int o = 32; o > 0; o >>= 1) {
        s  += __shfl_down(s, o);
        sq += __shfl_down(sq, o);
    }
    __shared__ float red[8];
    if ((tid & 63) == 0) { red[tid >> 6] = s; red[4 + (tid >> 6)] = sq; }
    __syncthreads();
    float st  = red[0] + red[1] + red[2] + red[3];
    float sqt = red[4] + red[5] + red[6] + red[7];
    float mu = st * (1.f / DIM);
    float var = sqt * (1.f / DIM) - mu * mu;
    float rstd = rsqrtf(var + 1e-6f);
    float4 g = ((const float4*)gamma)[tid];
    float4 bt = ((const float4*)beta)[tid];
    ushort4 ob;
    ob.x = to_bf16_bits((v.x - mu) * rstd * g.x + bt.x);
    ob.y = to_bf16_bits((v.y - mu) * rstd * g.y + bt.y);
    ob.z = to_bf16_bits((v.z - mu) * rstd * g.z + bt.z);
    ob.w = to_bf16_bits((v.w - mu) * rstd * g.w + bt.w);
    ((ushort4*)(out + (size_t)row * DIM))[tid] = ob;
}

// ---------------- bf16 MFMA GEMM, 64x64 tile, BK=64, double-buffered LDS ----------------
// ACT 0: outb = bf16(v) [tok][DIM], outf = silu(v) [tok][DIM].
// ACT 1: outb = bf16(softplus) [tok][DIM], outbT = bf16(softplus) transposed [DIM][NTOK].
// ACT 2: outbT = bf16(softplus) transposed [DIM][NTOK] only.
template<int ACT>
__global__ __launch_bounds__(256) void mfma_gemm(
    const ushort_t* __restrict__ A, const ushort_t* __restrict__ Bt,
    const float* __restrict__ bias, ushort_t* __restrict__ outb,
    ushort_t* __restrict__ outbT, float* __restrict__ outf) {
    __shared__ __align__(16) ushort_t Asl[2][64 * 64];
    __shared__ __align__(16) ushort_t Bsl[2][64 * 64];
    const int tid = threadIdx.x;
    const int bm = blockIdx.y * 64;
    const int bn = blockIdx.x * 64;
    const int lane = tid & 63;
    const int wid = tid >> 6;
    const int r  = lane & 15;
    const int kg = lane >> 4;            // 0..3
    const int wm = wid >> 1, wn = wid & 1;

    f32x4 acc[2][2] = {};

    auto STAGE = [&](int buf, int k0) {
        #pragma unroll
        for (int q = 0; q < 2; ++q) {
            int c = q * 256 + tid;
            int row = c >> 3;
            int ksl = ((c & 7) ^ (row & 7)) << 3;
            __builtin_amdgcn_global_load_lds(
                (const __attribute__((address_space(1))) void*)(A + (size_t)(bm + row) * DIM + k0 + ksl),
                (__attribute__((address_space(3))) void*)(&Asl[buf][c * 8]), 16, 0, 0);
        }
        #pragma unroll
        for (int q = 0; q < 2; ++q) {
            int c = q * 256 + tid;
            int row = c >> 3;
            int ksl = ((c & 7) ^ (row & 7)) << 3;
            __builtin_amdgcn_global_load_lds(
                (const __attribute__((address_space(1))) void*)(Bt + (size_t)(bn + row) * DIM + k0 + ksl),
                (__attribute__((address_space(3))) void*)(&Bsl[buf][c * 8]), 16, 0, 0);
        }
    };

    STAGE(0, 0);
    __syncthreads();                 // buf0 staged (syncthreads drains vmcnt)
    int cur = 0;
    for (int t = 0; t < DIM / 64; ++t) {
        if (t + 1 < DIM / 64) STAGE(cur ^ 1, (t + 1) * 64);   // issue next-tile loads
        #pragma unroll
        for (int kk = 0; kk < 2; ++kk) {
            const int sw = ((kk * 4 + kg) ^ (r & 7)) << 3;
            bf16x8 af[2], bfr[2];
            #pragma unroll
            for (int mi = 0; mi < 2; ++mi)
                af[mi] = *(const bf16x8*)&Asl[cur][(wm * 32 + mi * 16 + r) * 64 + sw];
            #pragma unroll
            for (int nj = 0; nj < 2; ++nj)
                bfr[nj] = *(const bf16x8*)&Bsl[cur][(wn * 32 + nj * 16 + r) * 64 + sw];
            #pragma unroll
            for (int mi = 0; mi < 2; ++mi)
                #pragma unroll
                for (int nj = 0; nj < 2; ++nj)
                    acc[mi][nj] = __builtin_amdgcn_mfma_f32_16x16x32_bf16(af[mi], bfr[nj], acc[mi][nj], 0, 0, 0);
        }
        __syncthreads();             // drains next-tile loads + everyone done reading cur
        cur ^= 1;
    }

    // epilogue: row = bm + wm*32 + mi*16 + kg*4 + j, col = bn + wn*32 + nj*16 + r
    #pragma unroll
    for (int nj = 0; nj < 2; ++nj) {
        const int col = bn + wn * 32 + nj * 16 + r;
        const float bv = bias[col];
        #pragma unroll
        for (int mi = 0; mi < 2; ++mi) {
            const int rowb = bm + wm * 32 + mi * 16 + kg * 4;
            if (ACT == 0) {
                #pragma unroll
                for (int j = 0; j < 4; ++j) {
                    float v = acc[mi][nj][j] + bv;
                    size_t idx = (size_t)(rowb + j) * DIM + col;
                    outb[idx] = to_bf16_bits(v);
                    outf[idx] = v / (1.f + __expf(-v));   // silu
                }
            } else {
                float sp[4];
                #pragma unroll
                for (int j = 0; j < 4; ++j)
                    sp[j] = softplus_f(acc[mi][nj][j] + bv);
                if (ACT == 1) {
                    #pragma unroll
                    for (int j = 0; j < 4; ++j)
                        outb[(size_t)(rowb + j) * DIM + col] = to_bf16_bits(sp[j]);
                }
                ushort4 tp;
                tp.x = to_bf16_bits(sp[0]); tp.y = to_bf16_bits(sp[1]);
                tp.z = to_bf16_bits(sp[2]); tp.w = to_bf16_bits(sp[3]);
                *(ushort4*)&outbT[(size_t)col * NTOK + rowb] = tp;
            }
        }
    }
}

// ---------------- Wcomb precompute ----------------
__global__ __launch_bounds__(256) void wcomb_kernel(
    const float* __restrict__ Wx1, const float* __restrict__ Wdt1,
    const float* __restrict__ bx1, const float* __restrict__ bdt1,
    const float* __restrict__ Wx2, const float* __restrict__ Wdt2,
    const float* __restrict__ bx2, const float* __restrict__ bdt2,
    ushort_t* __restrict__ WcombT, ushort_t* __restrict__ WxBCt,
    float* __restrict__ bcomb) {
    const int s = blockIdx.z;
    const float* __restrict__ Wx  = s ? Wx2  : Wx1;   // [1024][96]
    const float* __restrict__ Wdt = s ? Wdt2 : Wdt1;  // [64][1024]
    const float* __restrict__ bx  = s ? bx2  : bx1;
    const float* __restrict__ bdt = s ? bdt2 : bdt1;
    const int tid = threadIdx.x;
    __shared__ float Xs[64][65];   // [i][r]
    __shared__ float Ds[64][65];   // [r][j]
    if (blockIdx.y == 16) {
        const int i0 = blockIdx.x * 64;
        #pragma unroll
        for (int p = 0; p < 8; ++p) {
            int idx = p * 256 + tid;
            int c = idx >> 6, i = i0 + (idx & 63);
            WxBCt[((size_t)s * 32 + c) * DIM + i] = to_bf16_bits(Wx[(size_t)i * 96 + 64 + c]);
        }
        if (tid < 64) {
            int j = i0 + tid;
            float acc = bdt[j];
            for (int r = 0; r < 64; ++r) acc = fmaf(bx[r], Wdt[(size_t)r * DIM + j], acc);
            bcomb[(size_t)s * DIM + j] = acc;
        }
        return;
    }
    const int i0 = blockIdx.x * 64, j0 = blockIdx.y * 64;
    #pragma unroll
    for (int p = 0; p < 16; ++p) {
        int idx = p * 256 + tid;
        int i = idx >> 6, r = idx & 63;
        Xs[i][r] = Wx[(size_t)(i0 + i) * 96 + r];
    }
    #pragma unroll
    for (int p = 0; p < 16; ++p) {
        int idx = p * 256 + tid;
        int r = idx >> 6, j = idx & 63;
        Ds[r][j] = Wdt[(size_t)r * DIM + j0 + j];
    }
    __syncthreads();
    const int tj = (tid >> 4) * 4, ti = (tid & 15) * 4;
    float acc[4][4] = {};
    for (int r = 0; r < 64; ++r) {
        float a[4], b[4];
        #pragma unroll
        for (int q = 0; q < 4; ++q) a[q] = Ds[r][tj + q];
        #pragma unroll
        for (int q = 0; q < 4; ++q) b[q] = Xs[ti + q][r];
        #pragma unroll
        for (int ji = 0; ji < 4; ++ji)
            #pragma unroll
            for (int ii = 0; ii < 4; ++ii)
                acc[ji][ii] = fmaf(a[ji], b[ii], acc[ji][ii]);
    }
    #pragma unroll
    for (int ji = 0; ji < 4; ++ji)
        #pragma unroll
        for (int ii = 0; ii < 4; ++ii)
            WcombT[((size_t)s * DIM + j0 + tj + ji) * DIM + i0 + ti + ii] = to_bf16_bits(acc[ji][ii]);
}

// ---------------- BC^T = (u @ W_x[:,64:96] + b_x[64:96])^T, split-K MFMA + atomics ----------------
__global__ __launch_bounds__(256) void bc_kernel(
    const ushort_t* __restrict__ u1b, const ushort_t* __restrict__ u2b,
    const ushort_t* __restrict__ WxBCt,
    const float* __restrict__ bx1, const float* __restrict__ bx2,
    float* __restrict__ BCT) {
    const int s = blockIdx.z;
    const ushort_t* __restrict__ u  = s ? u2b : u1b;
    const ushort_t* __restrict__ Bt = WxBCt + (size_t)s * 32 * DIM;
    const float* __restrict__ bx    = s ? bx2 : bx1;
    const int bm = blockIdx.x * 64;
    const int kbase = blockIdx.y * 256;
    __shared__ __align__(16) ushort_t Asl[2][64 * 64];
    __shared__ __align__(16) ushort_t Bsl[2][32 * 64];
    const int tid = threadIdx.x;
    const int lane = tid & 63, wid = tid >> 6;
    const int r = lane & 15, kg = lane >> 4;
    f32x4 acc[2] = {};
    auto STAGE = [&](int buf, int k0) {
        #pragma unroll
        for (int q = 0; q < 2; ++q) {
            int c = q * 256 + tid;
            int row = c >> 3;
            int ksl = ((c & 7) ^ (row & 7)) << 3;
            __builtin_amdgcn_global_load_lds(
                (const __attribute__((address_space(1))) void*)(u + (size_t)(bm + row) * DIM + k0 + ksl),
                (__attribute__((address_space(3))) void*)(&Asl[buf][c * 8]), 16, 0, 0);
        }
        {
            int c = tid;
            int row = c >> 3;
            int ksl = ((c & 7) ^ (row & 7)) << 3;
            __builtin_amdgcn_global_load_lds(
                (const __attribute__((address_space(1))) void*)(Bt + (size_t)row * DIM + k0 + ksl),
                (__attribute__((address_space(3))) void*)(&Bsl[buf][c * 8]), 16, 0, 0);
        }
    };
    STAGE(0, kbase);
    __syncthreads();
    int cur = 0;
    for (int t = 0; t < 4; ++t) {
        if (t + 1 < 4) STAGE(cur ^ 1, kbase + (t + 1) * 64);
        #pragma unroll
        for (int kk = 0; kk < 2; ++kk) {
            const int sw = ((kk * 4 + kg) ^ (r & 7)) << 3;
            bf16x8 af = *(const bf16x8*)&Asl[cur][(wid * 16 + r) * 64 + sw];
            #pragma unroll
            for (int nj = 0; nj < 2; ++nj) {
                bf16x8 bfr = *(const bf16x8*)&Bsl[cur][(nj * 16 + r) * 64 + sw];
                acc[nj] = __builtin_amdgcn_mfma_f32_16x16x32_bf16(af, bfr, acc[nj], 0, 0, 0);
            }
        }
        __syncthreads();
        cur ^= 1;
    }
    const bool kc0 = (blockIdx.y == 0);
    #pragma unroll
    for (int nj = 0; nj < 2; ++nj) {
        const int col = nj * 16 + r;
        #pragma unroll
        for (int j = 0; j < 4; ++j) {
            const int row = bm + wid * 16 + kg * 4 + j;
            float v = acc[nj][j];
            if (kc0) v += bx[64 + col];
            atomicAdd(&BCT[((size_t)s * 32 + col) * NTOK + row], v);
        }
    }
}

// ---------------- chunked selective scan, vectorized transposed loads ----------------
// thread map (round-6 proven): n = tid&15, d = blockIdx.x*16 + (tid>>4) -> y stores coalesced.
// dT/uT bf16 [DIM][NTOK], BCT fp32 [2][32][NTOK].
// rbuf: [2][NB][NCH][DIM][DST] fp32 (4MB);  sdbuf: [2][NB][NCH][DIM] fp32 (0.25MB)
__global__ __launch_bounds__(256) void scan_pass1(
    const ushort_t* __restrict__ dT1, const ushort_t* __restrict__ uT1, const float* __restrict__ Alog1,
    const ushort_t* __restrict__ dT2, const ushort_t* __restrict__ uT2, const float* __restrict__ Alog2,
    const float* __restrict__ BCT, float* __restrict__ rbuf, float* __restrict__ sdbuf) {
    const int s = blockIdx.z;
    const ushort_t* __restrict__ dT = s ? dT2 : dT1;
    const ushort_t* __restrict__ uT = s ? uT2 : uT1;
    const float* __restrict__ Alog  = s ? Alog2 : Alog1;
    const int tid = threadIdx.x;
    const int n = tid & 15;
    const int d = blockIdx.x * 16 + (tid >> 4);
    const int b = blockIdx.y >> 3;
    const int c = blockIdx.y & 7;
    const int tok0 = b * LSEQ + c * TCH;
    const float a = -__expf(Alog[d * DST + n]);
    const ushort_t* __restrict__ dlp = dT + (size_t)d * NTOK + tok0;
    const ushort_t* __restrict__ uup = uT + (size_t)d * NTOK + tok0;
    const float* __restrict__ Bp = BCT + ((size_t)s * 32 + n) * NTOK + tok0;
    float h = 0.f, sd = 0.f;
    for (int t = 0; t < TCH; t += 8) {
        bf16x8 dl8 = *(const bf16x8*)(dlp + t);
        bf16x8 uu8 = *(const bf16x8*)(uup + t);
        f32x4 B0 = *(const f32x4*)(Bp + t);
        f32x4 B1 = *(const f32x4*)(Bp + t + 4);
        #pragma unroll
        for (int j = 0; j < 8; ++j) {
            float dl = bf16_bits_to_f((ushort_t)dl8[j]);
            float uu = bf16_bits_to_f((ushort_t)uu8[j]);
            float Bn = (j < 4) ? B0[j] : B1[j - 4];
            float e  = __expf(dl * a);
            h = fmaf(e, h, dl * Bn * uu);
            sd += dl;
        }
    }
    const size_t ridx = ((((size_t)s * NB + b) * NCH + c) * DIM + d) * DST + n;
    rbuf[ridx] = h;
    if (n == 0) sdbuf[(((size_t)s * NB + b) * NCH + c) * DIM + d] = sd;
}

__global__ __launch_bounds__(256) void scan_combine(
    const float* __restrict__ Alog1, const float* __restrict__ Alog2,
    float* __restrict__ rbuf, const float* __restrict__ sdbuf) {
    const int tid = threadIdx.x;
    const int sb = blockIdx.x >> 6;         // 0..7
    const int s = sb >> 2, b = sb & 3;
    const int flat = (blockIdx.x & 63) * 256 + tid;
    const int d = flat >> 4, n = flat & 15;
    const float* Alog = s ? Alog2 : Alog1;
    const float a = -__expf(Alog[d * DST + n]);
    float hprev = 0.f;
    #pragma unroll
    for (int c = 0; c < NCH; ++c) {
        const size_t ridx = ((((size_t)s * NB + b) * NCH + c) * DIM + d) * DST + n;
        float rc = rbuf[ridx];
        float P = __expf(a * sdbuf[(((size_t)s * NB + b) * NCH + c) * DIM + d]);
        float hnew = fmaf(P, hprev, rc);
        rbuf[ridx] = hprev;                 // overwrite r_c with hin_c
        hprev = hnew;
    }
}

__global__ __launch_bounds__(256) void scan_pass2(
    const ushort_t* __restrict__ dT1, const ushort_t* __restrict__ uT1,
    const float* __restrict__ Alog1, const float* __restrict__ D1p, float* __restrict__ y1,
    const ushort_t* __restrict__ dT2, const ushort_t* __restrict__ uT2,
    const float* __restrict__ Alog2, const float* __restrict__ D2p, float* __restrict__ y2,
    const float* __restrict__ BCT, const float* __restrict__ rbuf) {
    const int s = blockIdx.z;
    const ushort_t* __restrict__ dT = s ? dT2 : dT1;
    const ushort_t* __restrict__ uT = s ? uT2 : uT1;
    const float* __restrict__ Alog  = s ? Alog2 : Alog1;
    const float* __restrict__ Dp    = s ? D2p : D1p;
    float* __restrict__ y           = s ? y2 : y1;
    const int tid = threadIdx.x;
    const int n = tid & 15;
    const int d = blockIdx.x * 16 + (tid >> 4);
    const int b = blockIdx.y >> 3;
    const int c = blockIdx.y & 7;
    const int tok0 = b * LSEQ + c * TCH;
    const float a = -__expf(Alog[d * DST + n]);
    const float dcf = Dp[d];
    const ushort_t* __restrict__ dlp = dT + (size_t)d * NTOK + tok0;
    const ushort_t* __restrict__ uup = uT + (size_t)d * NTOK + tok0;
    const float* __restrict__ Bp = BCT + ((size_t)s * 32 + n) * NTOK + tok0;
    const float* __restrict__ Cp = Bp + 16 * NTOK;
    float h = rbuf[((((size_t)s * NB + b) * NCH + c) * DIM + d) * DST + n];  // hin
    float* __restrict__ yp = y + (size_t)tok0 * DIM + d;
    for (int t = 0; t < TCH; t += 8) {
        bf16x8 dl8 = *(const bf16x8*)(dlp + t);
        bf16x8 uu8 = *(const bf16x8*)(uup + t);
        f32x4 B0 = *(const f32x4*)(Bp + t);
        f32x4 B1 = *(const f32x4*)(Bp + t + 4);
        f32x4 C0 = *(const f32x4*)(Cp + t);
        f32x4 C1 = *(const f32x4*)(Cp + t + 4);
        #pragma unroll
        for (int j = 0; j < 8; ++j) {
            float dl = bf16_bits_to_f((ushort_t)dl8[j]);
            float uu = bf16_bits_to_f((ushort_t)uu8[j]);
            float Bn = (j < 4) ? B0[j] : B1[j - 4];
            float Cn = (j < 4) ? C0[j] : C1[j - 4];
            float e  = __expf(dl * a);
            h = fmaf(e, h, dl * Bn * uu);
            float p = h * Cn;
            p = dpp_add<0xB1>(p);
            p = dpp_add<0x4E>(p);
            p = dpp_add<0x124>(p);
            p = dpp_add<0x128>(p);
            if (n == 0) yp[(size_t)(t + j) * DIM] = fmaf(uu, dcf, p);
        }
    }
}

// ---------------- out = (y1 + y2) * z + skip  (z lives in d_out) ----------------
__global__ __launch_bounds__(256) void final_kernel(
    const float* __restrict__ y1, const float* __restrict__ y2,
    const float* __restrict__ skip, float* io) {
    const int i = blockIdx.x * 256 + threadIdx.x;
    float4 a = ((const float4*)y1)[i];
    float4 b = ((const float4*)y2)[i];
    float4 sk = ((const float4*)skip)[i];
    float4 z = ((float4*)io)[i];
    float4 o;
    o.x = (a.x + b.x) * z.x + sk.x;
    o.y = (a.y + b.y) * z.y + sk.y;
    o.z = (a.z + b.z) * z.z + sk.z;
    o.w = (a.w + b.w) * z.w + sk.w;
    ((float4*)io)[i] = o;
}

extern "C" void kernel_launch(void* const* d_in, const int* in_sizes, int n_in,
                              void* d_out, int out_size, void* d_ws, size_t ws_size,
                              hipStream_t stream) {
    const float* inputs = (const float*)d_in[0];
    const float* gamma  = (const float*)d_in[1];
    const float* beta   = (const float*)d_in[2];
    const float* W_proj = (const float*)d_in[3];
    const float* b_proj = (const float*)d_in[4];
    const float* W_fc   = (const float*)d_in[5];
    const float* b_fc   = (const float*)d_in[6];
    const float* W_bc   = (const float*)d_in[7];
    const float* b_bc   = (const float*)d_in[8];
    const float* W_x1   = (const float*)d_in[9];
    const float* b_x1   = (const float*)d_in[10];
    const float* W_dt1  = (const float*)d_in[11];
    const float* b_dt1  = (const float*)d_in[12];
    const float* A_log1 = (const float*)d_in[13];
    const float* D1     = (const float*)d_in[14];
    const float* W_x2   = (const float*)d_in[15];
    const float* b_x2   = (const float*)d_in[16];
    const float* W_dt2  = (const float*)d_in[17];
    const float* b_dt2  = (const float*)d_in[18];
    const float* A_log2 = (const float*)d_in[19];
    const float* D2     = (const float*)d_in[20];
    float* out = (float*)d_out;
    char* wsb  = (char*)d_ws;

    // workspace layout (~46.75 MB peak), liveness-overlaid:
    ushort_t* xln_bf   = (ushort_t*)wsb;                         // 0-4MB (dead after proj GEMM)
    ushort_t* proj_bf  = (ushort_t*)(wsb + (4u << 20));          // 4-8MB (dead after u GEMMs)
    float*    y1       = (float*)wsb;                            // 0-8MB (scan output; overlays xln/proj)
    ushort_t* u1t      = (ushort_t*)(wsb + (8u << 20));          // 8-12MB bf16 T [DIM][NTOK]
    ushort_t* u2t      = (ushort_t*)(wsb + (12u << 20));         // 12-16MB
    float*    y2       = (float*)(wsb + (16u << 20));            // 16-24MB
    ushort_t* u1b      = (ushort_t*)(wsb + (24u << 20));         // 24-28MB (dead after delta GEMMs)
    ushort_t* u2b      = (ushort_t*)(wsb + (28u << 20));         // 28-32MB
    ushort_t* delta1T  = (ushort_t*)(wsb + (32u << 20));         // 32-36MB bf16 T
    ushort_t* delta2T  = (ushort_t*)(wsb + (36u << 20));         // 36-40MB
    ushort_t* WtP      = (ushort_t*)(wsb + (40u << 20));         // 40-42MB (dead after proj GEMM)
    ushort_t* WtF      = (ushort_t*)(wsb + (42u << 20));         // 42-44MB (dead after u1 GEMM)
    ushort_t* WtB      = (ushort_t*)(wsb + (44u << 20));         // 44-46MB (dead after u2 GEMM)
    ushort_t* WxBCt    = (ushort_t*)(wsb + (40u << 20));         // 128KB (overlays WtP)
    float*    bcomb    = (float*)(wsb + (41u << 20));            // 8KB
    ushort_t* WcombT   = (ushort_t*)(wsb + (42u << 20));         // 4MB (overlays WtF/WtB; dead after delta GEMMs)
    float*    rbuf     = (float*)(wsb + (42u << 20));            // 4MB (overlays WcombT after delta GEMMs)
    float*    BCT      = (float*)(wsb + (46u << 20));            // 512KB [2][32][NTOK]
    float*    sdbuf    = (float*)(wsb + (46u << 20) + (512u << 10)); // 256KB
    float*    zbuf     = out;                                    // z = silu(proj) staged in d_out

    wconv_kernel<<<dim3(16, 16, 3), 256, 0, stream>>>(W_proj, W_fc, W_bc, WtP, WtF, WtB);
    ln_kernel<<<NTOK, 256, 0, stream>>>(inputs, gamma, beta, xln_bf);
    mfma_gemm<0><<<dim3(DIM / 64, NTOK / 64), 256, 0, stream>>>(xln_bf, WtP, b_proj, proj_bf, nullptr, zbuf);
    mfma_gemm<1><<<dim3(DIM / 64, NTOK / 64), 256, 0, stream>>>(proj_bf, WtF, b_fc, u1b, u1t, nullptr);
    mfma_gemm<1><<<dim3(DIM / 64, NTOK / 64), 256, 0, stream>>>(proj_bf, WtB, b_bc, u2b, u2t, nullptr);
    wcomb_kernel<<<dim3(16, 17, 2), 256, 0, stream>>>(W_x1, W_dt1, b_x1, b_dt1,
                                                      W_x2, W_dt2, b_x2, b_dt2,
                                                      WcombT, WxBCt, bcomb);
    hipMemsetAsync(BCT, 0, (size_t)2 * 32 * NTOK * sizeof(float), stream);
    bc_kernel<<<dim3(NTOK / 64, 4, 2), 256, 0, stream>>>(u1b, u2b, WxBCt, b_x1, b_x2, BCT);
    mfma_gemm<2><<<dim3(DIM / 64, NTOK / 64), 256, 0, stream>>>(u1b, WcombT, bcomb, nullptr, delta1T, nullptr);
    mfma_gemm<2><<<dim3(DIM / 64, NTOK / 64), 256, 0, stream>>>(u2b, WcombT + (size_t)DIM * DIM,
                                                                bcomb + DIM, nullptr, delta2T, nullptr);
    scan_pass1<<<dim3(DIM / 16, NB * NCH, 2), 256, 0, stream>>>(delta1T, u1t, A_log1,
                                                                delta2T, u2t, A_log2, BCT, rbuf, sdbuf);
    scan_combine<<<512, 256, 0, stream>>>(A_log1, A_log2, rbuf, sdbuf);
    scan_pass2<<<dim3(DIM / 16, NB * NCH, 2), 256, 0, stream>>>(delta1T, u1t, A_log1, D1, y1,
                                                                delta2T, u2t, A_log2, D2, y2, BCT, rbuf);
    final_kernel<<<(size_t)NTOK * DIM / 4 / 256, 256, 0, stream>>>(y1, y2, inputs, out);
}

// Round 11
// 325.950 us; speedup vs baseline: 1.2370x; 1.0909x over previous
//
#include <hip/hip_runtime.h>
#include <hip/hip_bf16.h>
#include <math.h>

#define DIM 1024
#define NTOK 2048   // B*L = 4*512
#define LSEQ 512
#define NB 4
#define DTR 64
#define DST 16
#define NCH 8
#define TCH 64      // LSEQ / NCH

typedef unsigned short ushort_t;
typedef __attribute__((ext_vector_type(8))) short bf16x8;
typedef __attribute__((ext_vector_type(4))) float f32x4;

__device__ __forceinline__ float softplus_f(float x) {
    return (x > 20.f) ? x : log1pf(__expf(x));
}
__device__ __forceinline__ ushort_t to_bf16_bits(float f) {
    __hip_bfloat16 h = __float2bfloat16(f);
    return *(ushort_t*)&h;
}
__device__ __forceinline__ float bf16_bits_to_f(ushort_t b) {
    return __uint_as_float(((unsigned int)b) << 16);
}
__device__ __forceinline__ float exp2_fast(float x) {   // D = 2^S0 (v_exp_f32)
    float r;
    asm("v_exp_f32 %0, %1" : "=v"(r) : "v"(x));
    return r;
}
// x + dpp_perm(x); ctrl: 0xB1=quad xor1, 0x4E=quad xor2, 0x124=row_ror:4, 0x128=row_ror:8
template<int CTRL>
__device__ __forceinline__ float dpp_add(float x) {
    int xi = __float_as_int(x);
    int yi = __builtin_amdgcn_update_dpp(xi, xi, CTRL, 0xF, 0xF, false);
    return x + __int_as_float(yi);
}

// ---------------- weight transpose + bf16 convert: Wt[n][k] = bf16(W[k][n]) ----------------
__global__ __launch_bounds__(256) void wconv_kernel(
    const float* __restrict__ W0, const float* __restrict__ W1, const float* __restrict__ W2,
    ushort_t* __restrict__ T0, ushort_t* __restrict__ T1, ushort_t* __restrict__ T2) {
    const float* W = blockIdx.z == 0 ? W0 : blockIdx.z == 1 ? W1 : W2;
    ushort_t* T    = blockIdx.z == 0 ? T0 : blockIdx.z == 1 ? T1 : T2;
    __shared__ float tile[64][65];
    const int k0 = blockIdx.x * 64, n0 = blockIdx.y * 64;
    const int tid = threadIdx.x;
    #pragma unroll
    for (int p = 0; p < 16; ++p) {
        int idx = p * 256 + tid;
        int i = idx >> 6, j = idx & 63;
        tile[i][j] = W[(size_t)(k0 + i) * DIM + n0 + j];
    }
    __syncthreads();
    #pragma unroll
    for (int p = 0; p < 16; ++p) {
        int idx = p * 256 + tid;
        int j = idx >> 6, i = idx & 63;
        T[(size_t)(n0 + j) * DIM + k0 + i] = to_bf16_bits(tile[i][j]);
    }
}

// ---------------- LayerNorm -> bf16 ----------------
__global__ __launch_bounds__(256) void ln_kernel(
    const float* __restrict__ x, const float* __restrict__ gamma,
    const float* __restrict__ beta, ushort_t* __restrict__ out) {
    const int row = blockIdx.x;
    const int tid = threadIdx.x;
    const float4* xr = (const float4*)(x + (size_t)row * DIM);
    float4 v = xr[tid];
    float s  = v.x + v.y + v.z + v.w;
    float sq = v.x*v.x + v.y*v.y + v.z*v.z + v.w*v.w;
    for (int o = 32; o > 0; o >>= 1) {
        s  += __shfl_down(s, o);
        sq += __shfl_down(sq, o);
    }
    __shared__ float red[8];
    if ((tid & 63) == 0) { red[tid >> 6] = s; red[4 + (tid >> 6)] = sq; }
    __syncthreads();
    float st  = red[0] + red[1] + red[2] + red[3];
    float sqt = red[4] + red[5] + red[6] + red[7];
    float mu = st * (1.f / DIM);
    float var = sqt * (1.f / DIM) - mu * mu;
    float rstd = rsqrtf(var + 1e-6f);
    float4 g = ((const float4*)gamma)[tid];
    float4 bt = ((const float4*)beta)[tid];
    ushort4 ob;
    ob.x = to_bf16_bits((v.x - mu) * rstd * g.x + bt.x);
    ob.y = to_bf16_bits((v.y - mu) * rstd * g.y + bt.y);
    ob.z = to_bf16_bits((v.z - mu) * rstd * g.z + bt.z);
    ob.w = to_bf16_bits((v.w - mu) * rstd * g.w + bt.w);
    ((ushort4*)(out + (size_t)row * DIM))[tid] = ob;
}

// ---------------- shared GEMM core: 64x64 tile, BK=64, dbuf LDS, 4 waves 2x2 ----------------
#define GEMM_CORE(A_, Bt_)                                                                  \
    __shared__ __align__(16) ushort_t Asl[2][64 * 64];                                      \
    __shared__ __align__(16) ushort_t Bsl[2][64 * 64];                                      \
    const int tid = threadIdx.x;                                                            \
    const int bm = blockIdx.y * 64;                                                         \
    const int bn = blockIdx.x * 64;                                                         \
    const int lane = tid & 63;                                                              \
    const int wid = tid >> 6;                                                               \
    const int r  = lane & 15;                                                               \
    const int kg = lane >> 4;                                                               \
    const int wm = wid >> 1, wn = wid & 1;                                                  \
    f32x4 acc[2][2] = {};                                                                   \
    auto STAGE = [&](int buf, int k0) {                                                     \
        _Pragma("unroll")                                                                   \
        for (int q = 0; q < 2; ++q) {                                                       \
            int c = q * 256 + tid;                                                          \
            int row = c >> 3;                                                               \
            int ksl = ((c & 7) ^ (row & 7)) << 3;                                           \
            __builtin_amdgcn_global_load_lds(                                               \
                (const __attribute__((address_space(1))) void*)(A_ + (size_t)(bm + row) * DIM + k0 + ksl), \
                (__attribute__((address_space(3))) void*)(&Asl[buf][c * 8]), 16, 0, 0);     \
        }                                                                                   \
        _Pragma("unroll")                                                                   \
        for (int q = 0; q < 2; ++q) {                                                       \
            int c = q * 256 + tid;                                                          \
            int row = c >> 3;                                                               \
            int ksl = ((c & 7) ^ (row & 7)) << 3;                                           \
            __builtin_amdgcn_global_load_lds(                                               \
                (const __attribute__((address_space(1))) void*)(Bt_ + (size_t)(bn + row) * DIM + k0 + ksl), \
                (__attribute__((address_space(3))) void*)(&Bsl[buf][c * 8]), 16, 0, 0);     \
        }                                                                                   \
    };                                                                                      \
    STAGE(0, 0);                                                                            \
    __syncthreads();                                                                        \
    int cur = 0;                                                                            \
    for (int t = 0; t < DIM / 64; ++t) {                                                    \
        if (t + 1 < DIM / 64) STAGE(cur ^ 1, (t + 1) * 64);                                 \
        _Pragma("unroll")                                                                   \
        for (int kk = 0; kk < 2; ++kk) {                                                    \
            const int sw = ((kk * 4 + kg) ^ (r & 7)) << 3;                                  \
            bf16x8 af[2], bfr[2];                                                           \
            _Pragma("unroll")                                                               \
            for (int mi = 0; mi < 2; ++mi)                                                  \
                af[mi] = *(const bf16x8*)&Asl[cur][(wm * 32 + mi * 16 + r) * 64 + sw];      \
            _Pragma("unroll")                                                               \
            for (int nj = 0; nj < 2; ++nj)                                                  \
                bfr[nj] = *(const bf16x8*)&Bsl[cur][(wn * 32 + nj * 16 + r) * 64 + sw];     \
            _Pragma("unroll")                                                               \
            for (int mi = 0; mi < 2; ++mi)                                                  \
                _Pragma("unroll")                                                           \
                for (int nj = 0; nj < 2; ++nj)                                              \
                    acc[mi][nj] = __builtin_amdgcn_mfma_f32_16x16x32_bf16(af[mi], bfr[nj], acc[mi][nj], 0, 0, 0); \
        }                                                                                   \
        __syncthreads();                                                                    \
        cur ^= 1;                                                                           \
    }

// ---------------- proj GEMM (ACT0): outb = bf16(v), outf = silu(v) ----------------
__global__ __launch_bounds__(256) void mfma_gemm_proj(
    const ushort_t* __restrict__ A, const ushort_t* __restrict__ Bt,
    const float* __restrict__ bias, ushort_t* __restrict__ outb, float* __restrict__ outf) {
    GEMM_CORE(A, Bt)
    #pragma unroll
    for (int nj = 0; nj < 2; ++nj) {
        const int col = bn + wn * 32 + nj * 16 + r;
        const float bv = bias[col];
        #pragma unroll
        for (int mi = 0; mi < 2; ++mi) {
            const int rowb = bm + wm * 32 + mi * 16 + kg * 4;
            #pragma unroll
            for (int j = 0; j < 4; ++j) {
                float v = acc[mi][nj][j] + bv;
                size_t idx = (size_t)(rowb + j) * DIM + col;
                outb[idx] = to_bf16_bits(v);
                outf[idx] = v / (1.f + __expf(-v));   // silu
            }
        }
    }
}

// ---------------- paired GEMM (z = 0/1): softplus epilogue ----------------
// ACT 1: outb [tok][DIM] + outbT [DIM][NTOK].  ACT 2: outbT only.
template<int ACT>
__global__ __launch_bounds__(256) void mfma_gemm_pair(
    const ushort_t* __restrict__ A0, const ushort_t* __restrict__ A1,
    const ushort_t* __restrict__ Bt0, const ushort_t* __restrict__ Bt1,
    const float* __restrict__ bias0, const float* __restrict__ bias1,
    ushort_t* __restrict__ outb0, ushort_t* __restrict__ outb1,
    ushort_t* __restrict__ outbT0, ushort_t* __restrict__ outbT1) {
    const int z = blockIdx.z;
    const ushort_t* __restrict__ A    = z ? A1 : A0;
    const ushort_t* __restrict__ Bt   = z ? Bt1 : Bt0;
    const float* __restrict__ bias    = z ? bias1 : bias0;
    ushort_t* __restrict__ outb       = z ? outb1 : outb0;
    ushort_t* __restrict__ outbT      = z ? outbT1 : outbT0;
    GEMM_CORE(A, Bt)
    #pragma unroll
    for (int nj = 0; nj < 2; ++nj) {
        const int col = bn + wn * 32 + nj * 16 + r;
        const float bv = bias[col];
        #pragma unroll
        for (int mi = 0; mi < 2; ++mi) {
            const int rowb = bm + wm * 32 + mi * 16 + kg * 4;
            float sp[4];
            #pragma unroll
            for (int j = 0; j < 4; ++j)
                sp[j] = softplus_f(acc[mi][nj][j] + bv);
            if (ACT == 1) {
                #pragma unroll
                for (int j = 0; j < 4; ++j)
                    outb[(size_t)(rowb + j) * DIM + col] = to_bf16_bits(sp[j]);
            }
            ushort4 tp;
            tp.x = to_bf16_bits(sp[0]); tp.y = to_bf16_bits(sp[1]);
            tp.z = to_bf16_bits(sp[2]); tp.w = to_bf16_bits(sp[3]);
            *(ushort4*)&outbT[(size_t)col * NTOK + rowb] = tp;
        }
    }
}

// ---------------- Wcomb precompute ----------------
__global__ __launch_bounds__(256) void wcomb_kernel(
    const float* __restrict__ Wx1, const float* __restrict__ Wdt1,
    const float* __restrict__ bx1, const float* __restrict__ bdt1,
    const float* __restrict__ Wx2, const float* __restrict__ Wdt2,
    const float* __restrict__ bx2, const float* __restrict__ bdt2,
    ushort_t* __restrict__ WcombT, ushort_t* __restrict__ WxBCt,
    float* __restrict__ bcomb) {
    const int s = blockIdx.z;
    const float* __restrict__ Wx  = s ? Wx2  : Wx1;   // [1024][96]
    const float* __restrict__ Wdt = s ? Wdt2 : Wdt1;  // [64][1024]
    const float* __restrict__ bx  = s ? bx2  : bx1;
    const float* __restrict__ bdt = s ? bdt2 : bdt1;
    const int tid = threadIdx.x;
    __shared__ float Xs[64][65];   // [i][r]
    __shared__ float Ds[64][65];   // [r][j]
    if (blockIdx.y == 16) {
        const int i0 = blockIdx.x * 64;
        #pragma unroll
        for (int p = 0; p < 8; ++p) {
            int idx = p * 256 + tid;
            int c = idx >> 6, i = i0 + (idx & 63);
            WxBCt[((size_t)s * 32 + c) * DIM + i] = to_bf16_bits(Wx[(size_t)i * 96 + 64 + c]);
        }
        if (tid < 64) {
            int j = i0 + tid;
            float acc = bdt[j];
            for (int r = 0; r < 64; ++r) acc = fmaf(bx[r], Wdt[(size_t)r * DIM + j], acc);
            bcomb[(size_t)s * DIM + j] = acc;
        }
        return;
    }
    const int i0 = blockIdx.x * 64, j0 = blockIdx.y * 64;
    #pragma unroll
    for (int p = 0; p < 16; ++p) {
        int idx = p * 256 + tid;
        int i = idx >> 6, r = idx & 63;
        Xs[i][r] = Wx[(size_t)(i0 + i) * 96 + r];
    }
    #pragma unroll
    for (int p = 0; p < 16; ++p) {
        int idx = p * 256 + tid;
        int r = idx >> 6, j = idx & 63;
        Ds[r][j] = Wdt[(size_t)r * DIM + j0 + j];
    }
    __syncthreads();
    const int tj = (tid >> 4) * 4, ti = (tid & 15) * 4;
    float acc[4][4] = {};
    for (int r = 0; r < 64; ++r) {
        float a[4], b[4];
        #pragma unroll
        for (int q = 0; q < 4; ++q) a[q] = Ds[r][tj + q];
        #pragma unroll
        for (int q = 0; q < 4; ++q) b[q] = Xs[ti + q][r];
        #pragma unroll
        for (int ji = 0; ji < 4; ++ji)
            #pragma unroll
            for (int ii = 0; ii < 4; ++ii)
                acc[ji][ii] = fmaf(a[ji], b[ii], acc[ji][ii]);
    }
    #pragma unroll
    for (int ji = 0; ji < 4; ++ji)
        #pragma unroll
        for (int ii = 0; ii < 4; ++ii)
            WcombT[((size_t)s * DIM + j0 + tj + ji) * DIM + i0 + ti + ii] = to_bf16_bits(acc[ji][ii]);
}

// ---------------- BC^T = (u @ W_x[:,64:96] + b_x[64:96])^T, split-K MFMA + atomics ----------------
__global__ __launch_bounds__(256) void bc_kernel(
    const ushort_t* __restrict__ u1b, const ushort_t* __restrict__ u2b,
    const ushort_t* __restrict__ WxBCt,
    const float* __restrict__ bx1, const float* __restrict__ bx2,
    float* __restrict__ BCT) {
    const int s = blockIdx.z;
    const ushort_t* __restrict__ u  = s ? u2b : u1b;
    const ushort_t* __restrict__ Bt = WxBCt + (size_t)s * 32 * DIM;
    const float* __restrict__ bx    = s ? bx2 : bx1;
    const int bm = blockIdx.x * 64;
    const int kbase = blockIdx.y * 256;
    __shared__ __align__(16) ushort_t Asl[2][64 * 64];
    __shared__ __align__(16) ushort_t Bsl[2][32 * 64];
    const int tid = threadIdx.x;
    const int lane = tid & 63, wid = tid >> 6;
    const int r = lane & 15, kg = lane >> 4;
    f32x4 acc[2] = {};
    auto STAGE = [&](int buf, int k0) {
        #pragma unroll
        for (int q = 0; q < 2; ++q) {
            int c = q * 256 + tid;
            int row = c >> 3;
            int ksl = ((c & 7) ^ (row & 7)) << 3;
            __builtin_amdgcn_global_load_lds(
                (const __attribute__((address_space(1))) void*)(u + (size_t)(bm + row) * DIM + k0 + ksl),
                (__attribute__((address_space(3))) void*)(&Asl[buf][c * 8]), 16, 0, 0);
        }
        {
            int c = tid;
            int row = c >> 3;
            int ksl = ((c & 7) ^ (row & 7)) << 3;
            __builtin_amdgcn_global_load_lds(
                (const __attribute__((address_space(1))) void*)(Bt + (size_t)row * DIM + k0 + ksl),
                (__attribute__((address_space(3))) void*)(&Bsl[buf][c * 8]), 16, 0, 0);
        }
    };
    STAGE(0, kbase);
    __syncthreads();
    int cur = 0;
    for (int t = 0; t < 4; ++t) {
        if (t + 1 < 4) STAGE(cur ^ 1, kbase + (t + 1) * 64);
        #pragma unroll
        for (int kk = 0; kk < 2; ++kk) {
            const int sw = ((kk * 4 + kg) ^ (r & 7)) << 3;
            bf16x8 af = *(const bf16x8*)&Asl[cur][(wid * 16 + r) * 64 + sw];
            #pragma unroll
            for (int nj = 0; nj < 2; ++nj) {
                bf16x8 bfr = *(const bf16x8*)&Bsl[cur][(nj * 16 + r) * 64 + sw];
                acc[nj] = __builtin_amdgcn_mfma_f32_16x16x32_bf16(af, bfr, acc[nj], 0, 0, 0);
            }
        }
        __syncthreads();
        cur ^= 1;
    }
    const bool kc0 = (blockIdx.y == 0);
    #pragma unroll
    for (int nj = 0; nj < 2; ++nj) {
        const int col = nj * 16 + r;
        #pragma unroll
        for (int j = 0; j < 4; ++j) {
            const int row = bm + wid * 16 + kg * 4 + j;
            float v = acc[nj][j];
            if (kc0) v += bx[64 + col];
            atomicAdd(&BCT[((size_t)s * 32 + col) * NTOK + row], v);
        }
    }
}

// ---------------- chunked selective scan, vectorized + register-prefetch pipeline ----------------
// thread map (round-6 proven): n = tid&15, d = blockIdx.x*16 + (tid>>4) -> coalesced y stores.
// dT/uT bf16 [DIM][NTOK], BCT fp32 [2][32][NTOK]. a2 = a*log2(e); exp via v_exp_f32.
__device__ __forceinline__ void scan8_p1(bf16x8 dl8, bf16x8 uu8, f32x4 B0, f32x4 B1,
                                         float a2, float& h, float& sd) {
    #pragma unroll
    for (int j = 0; j < 8; ++j) {
        float dl = bf16_bits_to_f((ushort_t)dl8[j]);
        float uu = bf16_bits_to_f((ushort_t)uu8[j]);
        float Bn = (j < 4) ? B0[j] : B1[j - 4];
        float e  = exp2_fast(dl * a2);
        h = fmaf(e, h, dl * Bn * uu);
        sd += dl;
    }
}

__global__ __launch_bounds__(256) void scan_pass1(
    const ushort_t* __restrict__ dT1, const ushort_t* __restrict__ uT1, const float* __restrict__ Alog1,
    const ushort_t* __restrict__ dT2, const ushort_t* __restrict__ uT2, const float* __restrict__ Alog2,
    const float* __restrict__ BCT, float* __restrict__ rbuf, float* __restrict__ sdbuf) {
    const int s = blockIdx.z;
    const ushort_t* __restrict__ dT = s ? dT2 : dT1;
    const ushort_t* __restrict__ uT = s ? uT2 : uT1;
    const float* __restrict__ Alog  = s ? Alog2 : Alog1;
    const int tid = threadIdx.x;
    const int n = tid & 15;
    const int d = blockIdx.x * 16 + (tid >> 4);
    const int b = blockIdx.y >> 3;
    const int c = blockIdx.y & 7;
    const int tok0 = b * LSEQ + c * TCH;
    const float a2 = -__expf(Alog[d * DST + n]) * 1.44269504f;
    const ushort_t* __restrict__ dlp = dT + (size_t)d * NTOK + tok0;
    const ushort_t* __restrict__ uup = uT + (size_t)d * NTOK + tok0;
    const float* __restrict__ Bp = BCT + ((size_t)s * 32 + n) * NTOK + tok0;
    float h = 0.f, sd = 0.f;
    bf16x8 dlA, uuA, dlB, uuB;
    f32x4 B0A, B1A, B0B, B1B;
    dlA = *(const bf16x8*)(dlp);  uuA = *(const bf16x8*)(uup);
    B0A = *(const f32x4*)(Bp);    B1A = *(const f32x4*)(Bp + 4);
    for (int t = 0; t < TCH; t += 16) {
        dlB = *(const bf16x8*)(dlp + t + 8);  uuB = *(const bf16x8*)(uup + t + 8);
        B0B = *(const f32x4*)(Bp + t + 8);    B1B = *(const f32x4*)(Bp + t + 12);
        scan8_p1(dlA, uuA, B0A, B1A, a2, h, sd);
        if (t + 16 < TCH) {
            dlA = *(const bf16x8*)(dlp + t + 16);  uuA = *(const bf16x8*)(uup + t + 16);
            B0A = *(const f32x4*)(Bp + t + 16);    B1A = *(const f32x4*)(Bp + t + 20);
        }
        scan8_p1(dlB, uuB, B0B, B1B, a2, h, sd);
    }
    const size_t ridx = ((((size_t)s * NB + b) * NCH + c) * DIM + d) * DST + n;
    rbuf[ridx] = h;
    if (n == 0) sdbuf[(((size_t)s * NB + b) * NCH + c) * DIM + d] = sd;
}

__global__ __launch_bounds__(256) void scan_combine(
    const float* __restrict__ Alog1, const float* __restrict__ Alog2,
    float* __restrict__ rbuf, const float* __restrict__ sdbuf) {
    const int tid = threadIdx.x;
    const int sb = blockIdx.x >> 6;         // 0..7
    const int s = sb >> 2, b = sb & 3;
    const int flat = (blockIdx.x & 63) * 256 + tid;
    const int d = flat >> 4, n = flat & 15;
    const float* Alog = s ? Alog2 : Alog1;
    const float a2 = -__expf(Alog[d * DST + n]) * 1.44269504f;
    float hprev = 0.f;
    #pragma unroll
    for (int c = 0; c < NCH; ++c) {
        const size_t ridx = ((((size_t)s * NB + b) * NCH + c) * DIM + d) * DST + n;
        float rc = rbuf[ridx];
        float P = exp2_fast(a2 * sdbuf[(((size_t)s * NB + b) * NCH + c) * DIM + d]);
        float hnew = fmaf(P, hprev, rc);
        rbuf[ridx] = hprev;                 // overwrite r_c with hin_c
        hprev = hnew;
    }
}

__device__ __forceinline__ void scan8_p2(bf16x8 dl8, bf16x8 uu8, f32x4 B0, f32x4 B1,
                                         f32x4 C0, f32x4 C1, float a2, float dcf,
                                         int n, float* __restrict__ yp, float& h) {
    #pragma unroll
    for (int j = 0; j < 8; ++j) {
        float dl = bf16_bits_to_f((ushort_t)dl8[j]);
        float uu = bf16_bits_to_f((ushort_t)uu8[j]);
        float Bn = (j < 4) ? B0[j] : B1[j - 4];
        float Cn = (j < 4) ? C0[j] : C1[j - 4];
        float e  = exp2_fast(dl * a2);
        h = fmaf(e, h, dl * Bn * uu);
        float p = h * Cn;
        p = dpp_add<0xB1>(p);
        p = dpp_add<0x4E>(p);
        p = dpp_add<0x124>(p);
        p = dpp_add<0x128>(p);
        if (n == 0) yp[(size_t)j * DIM] = fmaf(uu, dcf, p);
    }
}

__global__ __launch_bounds__(256) void scan_pass2(
    const ushort_t* __restrict__ dT1, const ushort_t* __restrict__ uT1,
    const float* __restrict__ Alog1, const float* __restrict__ D1p, float* __restrict__ y1,
    const ushort_t* __restrict__ dT2, const ushort_t* __restrict__ uT2,
    const float* __restrict__ Alog2, const float* __restrict__ D2p, float* __restrict__ y2,
    const float* __restrict__ BCT, const float* __restrict__ rbuf) {
    const int s = blockIdx.z;
    const ushort_t* __restrict__ dT = s ? dT2 : dT1;
    const ushort_t* __restrict__ uT = s ? uT2 : uT1;
    const float* __restrict__ Alog  = s ? Alog2 : Alog1;
    const float* __restrict__ Dp    = s ? D2p : D1p;
    float* __restrict__ y           = s ? y2 : y1;
    const int tid = threadIdx.x;
    const int n = tid & 15;
    const int d = blockIdx.x * 16 + (tid >> 4);
    const int b = blockIdx.y >> 3;
    const int c = blockIdx.y & 7;
    const int tok0 = b * LSEQ + c * TCH;
    const float a2 = -__expf(Alog[d * DST + n]) * 1.44269504f;
    const float dcf = Dp[d];
    const ushort_t* __restrict__ dlp = dT + (size_t)d * NTOK + tok0;
    const ushort_t* __restrict__ uup = uT + (size_t)d * NTOK + tok0;
    const float* __restrict__ Bp = BCT + ((size_t)s * 32 + n) * NTOK + tok0;
    const float* __restrict__ Cp = Bp + 16 * NTOK;
    float h = rbuf[((((size_t)s * NB + b) * NCH + c) * DIM + d) * DST + n];  // hin
    float* __restrict__ yp = y + (size_t)tok0 * DIM + d;
    bf16x8 dlA, uuA, dlB, uuB;
    f32x4 B0A, B1A, C0A, C1A, B0B, B1B, C0B, C1B;
    dlA = *(const bf16x8*)(dlp);  uuA = *(const bf16x8*)(uup);
    B0A = *(const f32x4*)(Bp);    B1A = *(const f32x4*)(Bp + 4);
    C0A = *(const f32x4*)(Cp);    C1A = *(const f32x4*)(Cp + 4);
    for (int t = 0; t < TCH; t += 16) {
        dlB = *(const bf16x8*)(dlp + t + 8);  uuB = *(const bf16x8*)(uup + t + 8);
        B0B = *(const f32x4*)(Bp + t + 8);    B1B = *(const f32x4*)(Bp + t + 12);
        C0B = *(const f32x4*)(Cp + t + 8);    C1B = *(const f32x4*)(Cp + t + 12);
        scan8_p2(dlA, uuA, B0A, B1A, C0A, C1A, a2, dcf, n, yp + (size_t)t * DIM, h);
        if (t + 16 < TCH) {
            dlA = *(const bf16x8*)(dlp + t + 16);  uuA = *(const bf16x8*)(uup + t + 16);
            B0A = *(const f32x4*)(Bp + t + 16);    B1A = *(const f32x4*)(Bp + t + 20);
            C0A = *(const f32x4*)(Cp + t + 16);    C1A = *(const f32x4*)(Cp + t + 20);
        }
        scan8_p2(dlB, uuB, B0B, B1B, C0B, C1B, a2, dcf, n, yp + (size_t)(t + 8) * DIM, h);
    }
}

// ---------------- out = (y1 + y2) * z + skip  (z lives in d_out) ----------------
__global__ __launch_bounds__(256) void final_kernel(
    const float* __restrict__ y1, const float* __restrict__ y2,
    const float* __restrict__ skip, float* io) {
    const int i = blockIdx.x * 256 + threadIdx.x;
    float4 a = ((const float4*)y1)[i];
    float4 b = ((const float4*)y2)[i];
    float4 sk = ((const float4*)skip)[i];
    float4 z = ((float4*)io)[i];
    float4 o;
    o.x = (a.x + b.x) * z.x + sk.x;
    o.y = (a.y + b.y) * z.y + sk.y;
    o.z = (a.z + b.z) * z.z + sk.z;
    o.w = (a.w + b.w) * z.w + sk.w;
    ((float4*)io)[i] = o;
}

extern "C" void kernel_launch(void* const* d_in, const int* in_sizes, int n_in,
                              void* d_out, int out_size, void* d_ws, size_t ws_size,
                              hipStream_t stream) {
    const float* inputs = (const float*)d_in[0];
    const float* gamma  = (const float*)d_in[1];
    const float* beta   = (const float*)d_in[2];
    const float* W_proj = (const float*)d_in[3];
    const float* b_proj = (const float*)d_in[4];
    const float* W_fc   = (const float*)d_in[5];
    const float* b_fc   = (const float*)d_in[6];
    const float* W_bc   = (const float*)d_in[7];
    const float* b_bc   = (const float*)d_in[8];
    const float* W_x1   = (const float*)d_in[9];
    const float* b_x1   = (const float*)d_in[10];
    const float* W_dt1  = (const float*)d_in[11];
    const float* b_dt1  = (const float*)d_in[12];
    const float* A_log1 = (const float*)d_in[13];
    const float* D1     = (const float*)d_in[14];
    const float* W_x2   = (const float*)d_in[15];
    const float* b_x2   = (const float*)d_in[16];
    const float* W_dt2  = (const float*)d_in[17];
    const float* b_dt2  = (const float*)d_in[18];
    const float* A_log2 = (const float*)d_in[19];
    const float* D2     = (const float*)d_in[20];
    float* out = (float*)d_out;
    char* wsb  = (char*)d_ws;

    // workspace layout (~46.75 MB peak), liveness-overlaid:
    ushort_t* xln_bf   = (ushort_t*)wsb;                         // 0-4MB (dead after proj GEMM)
    ushort_t* proj_bf  = (ushort_t*)(wsb + (4u << 20));          // 4-8MB (dead after u GEMMs)
    float*    y1       = (float*)wsb;                            // 0-8MB (scan output; overlays xln/proj)
    ushort_t* u1t      = (ushort_t*)(wsb + (8u << 20));          // 8-12MB bf16 T [DIM][NTOK]
    ushort_t* u2t      = (ushort_t*)(wsb + (12u << 20));         // 12-16MB
    float*    y2       = (float*)(wsb + (16u << 20));            // 16-24MB
    ushort_t* u1b      = (ushort_t*)(wsb + (24u << 20));         // 24-28MB (dead after delta GEMMs)
    ushort_t* u2b      = (ushort_t*)(wsb + (28u << 20));         // 28-32MB
    ushort_t* delta1T  = (ushort_t*)(wsb + (32u << 20));         // 32-36MB bf16 T
    ushort_t* delta2T  = (ushort_t*)(wsb + (36u << 20));         // 36-40MB
    ushort_t* WtP      = (ushort_t*)(wsb + (40u << 20));         // 40-42MB (dead after proj GEMM)
    ushort_t* WtF      = (ushort_t*)(wsb + (42u << 20));         // 42-44MB (dead after u GEMMs)
    ushort_t* WtB      = (ushort_t*)(wsb + (44u << 20));         // 44-46MB (dead after u GEMMs)
    ushort_t* WxBCt    = (ushort_t*)(wsb + (40u << 20));         // 128KB (overlays WtP)
    float*    bcomb    = (float*)(wsb + (41u << 20));            // 8KB
    ushort_t* WcombT   = (ushort_t*)(wsb + (42u << 20));         // 4MB (overlays WtF/WtB; dead after delta GEMMs)
    float*    rbuf     = (float*)(wsb + (42u << 20));            // 4MB (overlays WcombT after delta GEMMs)
    float*    BCT      = (float*)(wsb + (46u << 20));            // 512KB [2][32][NTOK]
    float*    sdbuf    = (float*)(wsb + (46u << 20) + (512u << 10)); // 256KB
    float*    zbuf     = out;                                    // z = silu(proj) staged in d_out

    wconv_kernel<<<dim3(16, 16, 3), 256, 0, stream>>>(W_proj, W_fc, W_bc, WtP, WtF, WtB);
    ln_kernel<<<NTOK, 256, 0, stream>>>(inputs, gamma, beta, xln_bf);
    mfma_gemm_proj<<<dim3(DIM / 64, NTOK / 64), 256, 0, stream>>>(xln_bf, WtP, b_proj, proj_bf, zbuf);
    mfma_gemm_pair<1><<<dim3(DIM / 64, NTOK / 64, 2), 256, 0, stream>>>(
        proj_bf, proj_bf, WtF, WtB, b_fc, b_bc, u1b, u2b, u1t, u2t);
    wcomb_kernel<<<dim3(16, 17, 2), 256, 0, stream>>>(W_x1, W_dt1, b_x1, b_dt1,
                                                      W_x2, W_dt2, b_x2, b_dt2,
                                                      WcombT, WxBCt, bcomb);
    hipMemsetAsync(BCT, 0, (size_t)2 * 32 * NTOK * sizeof(float), stream);
    bc_kernel<<<dim3(NTOK / 64, 4, 2), 256, 0, stream>>>(u1b, u2b, WxBCt, b_x1, b_x2, BCT);
    mfma_gemm_pair<2><<<dim3(DIM / 64, NTOK / 64, 2), 256, 0, stream>>>(
        u1b, u2b, WcombT, WcombT + (size_t)DIM * DIM, bcomb, bcomb + DIM,
        nullptr, nullptr, delta1T, delta2T);
    scan_pass1<<<dim3(DIM / 16, NB * NCH, 2), 256, 0, stream>>>(delta1T, u1t, A_log1,
                                                                delta2T, u2t, A_log2, BCT, rbuf, sdbuf);
    scan_combine<<<512, 256, 0, stream>>>(A_log1, A_log2, rbuf, sdbuf);
    scan_pass2<<<dim3(DIM / 16, NB * NCH, 2), 256, 0, stream>>>(delta1T, u1t, A_log1, D1, y1,
                                                                delta2T, u2t, A_log2, D2, y2, BCT, rbuf);
    final_kernel<<<(size_t)NTOK * DIM / 4 / 256, 256, 0, stream>>>(y1, y2, inputs, out);
}